// Round 13
// baseline (227.410 us; speedup 1.0000x reference)
//
#include <hip/hip_runtime.h>
#include <math.h>

#define BB 64
#define TT 2048
#define DD 512
#define UU 10
#define S_CHUNKS 16
#define CHUNK_T (TT / S_CHUNKS)   // 128 t per block, 32 per wave, 8 batches of 4
#define NB (CHUNK_T / 16)         // 8 batches per wave

__device__ __forceinline__ float fast_tanh(float x) {
    // tanh(x) = 1 - 2/(1+e^{2x}); robust at +-inf
    return 1.0f - 2.0f / (1.0f + __expf(2.0f * x));
}

// DPP row_shr:K accumulate (VALU pipe). Proven R5/R9/R10/R12.
template<int K>
__device__ __forceinline__ float dpp_shr(float x) {
    int xi = __builtin_bit_cast(int, x);
    int r  = __builtin_amdgcn_update_dpp(0, xi, 0x110 | K, 0xF, 0xF, true);
    return __builtin_bit_cast(float, r);
}

__device__ __forceinline__ float read_lane_f(float v, int lane) {
    return __builtin_bit_cast(float,
        __builtin_amdgcn_readlane(__builtin_bit_cast(int, v), lane));
}

// Async global->LDS DMA, 16B per lane (proven R12 with vmcnt(1) discipline).
typedef __attribute__((address_space(1))) const void gvoid;
typedef __attribute__((address_space(3))) void lvoid;
__device__ __forceinline__ void dma16(const float* g, float* l) {
    __builtin_amdgcn_global_load_lds((gvoid*)g, (lvoid*)l, 16, 0, 0);
}

// Resets the last-block counters each call (deterministic across replays;
// avoids hipMemsetAsync to keep graph capture risk at zero).
__global__ void zero_cnt(int* __restrict__ cnt) {
    if ((int)threadIdx.x < BB) cnt[threadIdx.x] = 0;
}

// R13 = R12's proven pass1 (LDS-DMA dbuf, vmcnt(1)) + fused last-block-done
// epilogue: the 16th finisher of batch b acquires (device fence) and computes
// l, context, weights for b in-place — removes the second kernel launch gap
// and overlaps epilogue with other batches' tails. Epilogue output is a pure
// function of pexp/pc => deterministic regardless of finish order.
__global__ __launch_bounds__(256) void attn_fused(
    const float* __restrict__ Eo, const float* __restrict__ H,
    const float* __restrict__ W_eo, const float* __restrict__ b_eo,
    const float* __restrict__ W_h, const float* __restrict__ b_h,
    const float* __restrict__ W_s, const float* __restrict__ b_s,
    float* __restrict__ pexp, float* __restrict__ pc,
    int* __restrict__ cnt,
    float* __restrict__ ctx_out, float* __restrict__ wout)
{
    const int b     = blockIdx.y;
    const int chunk = blockIdx.x;
    const int tid   = threadIdx.x;
    const int wave  = tid >> 6;
    const int lane  = tid & 63;

    __shared__ __align__(16) float buf[4][2][4][DD];  // 64 KB: per-wave dbuf tiles
    __shared__ float sc[4][DD];                        // 8 KB: wave combine
    __shared__ float sl[4];
    __shared__ int   s_last;

    // ---- hb[u] = (H[b]*W_h)[u] + b_h[u] + b_eo[u]  (once per wave)
    float hacc[UU];
    #pragma unroll
    for (int u = 0; u < UU; ++u) hacc[u] = 0.f;
    const float* Hb = H + (size_t)b * DD;
    #pragma unroll
    for (int k = 0; k < DD / 64; ++k) {
        float hv = Hb[k * 64 + lane];
        const float* wr = W_h + (size_t)(k * 64 + lane) * UU;
        #pragma unroll
        for (int u = 0; u < UU; ++u) hacc[u] += hv * wr[u];
    }
    #pragma unroll
    for (int off = 1; off < 64; off <<= 1) {
        #pragma unroll
        for (int u = 0; u < UU; ++u) hacc[u] += __shfl_xor(hacc[u], off, 64);
    }
    float hb[UU];
    #pragma unroll
    for (int u = 0; u < UU; ++u) hb[u] = hacc[u] + b_h[u] + b_eo[u];

    float wsv[UU];
    #pragma unroll
    for (int u = 0; u < UU; ++u) wsv[u] = W_s[u];   // uniform -> scalar loads
    const float bs = b_s[0];

    // ---- per-lane W_eo slice (80 VGPRs, loaded once, reused for all t)
    float wv[8][UU];
    #pragma unroll
    for (int k = 0; k < 2; ++k) {
        #pragma unroll
        for (int j = 0; j < 4; ++j) {
            const float* wr = W_eo + (size_t)(k * 256 + 4 * lane + j) * UU;
            #pragma unroll
            for (int u = 0; u < UU; ++u) wv[k * 4 + j][u] = wr[u];
        }
    }

    float l = 0.f;
    float c[8];
    #pragma unroll
    for (int j = 0; j < 8; ++j) c[j] = 0.f;

    const int  t0w  = chunk * CHUNK_T + wave * (CHUNK_T / 4);
    const bool lo32 = (lane & 32) == 0;
    const bool lo16 = (lane & 16) == 0;
    const float* rowb = Eo + (size_t)b * TT * DD + 4 * lane;   // per-lane src

    // ---- prologue: DMA tile 0
    #pragma unroll
    for (int tt = 0; tt < 4; ++tt) {
        const float* g = rowb + (size_t)(t0w + tt) * DD;
        dma16(g,       &buf[wave][0][tt][0]);
        dma16(g + 256, &buf[wave][0][tt][256]);
    }

    auto do_batch = [&](int i) {
        const int cur = i & 1, nxt = cur ^ 1;
        if (i + 1 < NB) {
            #pragma unroll
            for (int tt = 0; tt < 4; ++tt) {
                const float* g = rowb + (size_t)(t0w + (i + 1) * 4 + tt) * DD;
                dma16(g,       &buf[wave][nxt][tt][0]);
                dma16(g + 256, &buf[wave][nxt][tt][256]);
            }
        }
        __builtin_amdgcn_sched_barrier(0);   // pin issues before compute

        const int tb = t0w + i * 4;
        float e[4][8];
        #pragma unroll
        for (int tt = 0; tt < 4; ++tt) {
            float4 e0 = *(const float4*)&buf[wave][cur][tt][4 * lane];
            float4 e1 = *(const float4*)&buf[wave][cur][tt][256 + 4 * lane];
            e[tt][0] = e0.x; e[tt][1] = e0.y; e[tt][2] = e0.z; e[tt][3] = e0.w;
            e[tt][4] = e1.x; e[tt][5] = e1.y; e[tt][6] = e1.z; e[tt][7] = e1.w;
        }

        float acc[4][UU];
        #pragma unroll
        for (int tt = 0; tt < 4; ++tt) {
            #pragma unroll
            for (int u = 0; u < UU; ++u) acc[tt][u] = 0.f;
            #pragma unroll
            for (int j = 0; j < 8; ++j) {
                #pragma unroll
                for (int u = 0; u < UU; ++u) acc[tt][u] += e[tt][j] * wv[j][u];
            }
        }

        // fold-reduce (R5-proven): select+xor32 x2, select+xor16, 4x DPP
        float s = bs;
        #pragma unroll
        for (int u = 0; u < UU; ++u) {
            float y0 = lo32 ? acc[0][u] : acc[2][u];
            float o0 = lo32 ? acc[2][u] : acc[0][u];
            y0 += __shfl_xor(o0, 32, 64);
            float y1 = lo32 ? acc[1][u] : acc[3][u];
            float o1 = lo32 ? acc[3][u] : acc[1][u];
            y1 += __shfl_xor(o1, 32, 64);
            float z  = lo16 ? y0 : y1;
            float oz = lo16 ? y1 : y0;
            z += __shfl_xor(oz, 16, 64);
            z += dpp_shr<1>(z);
            z += dpp_shr<2>(z);
            z += dpp_shr<4>(z);
            z += dpp_shr<8>(z);
            s += wsv[u] * fast_tanh(z + hb[u]);
        }
        float p = __expf(s);

        if ((lane & 15) == 15) pexp[(size_t)b * TT + tb + (lane >> 4)] = p;

        float p0 = read_lane_f(p, 15);
        float p1 = read_lane_f(p, 31);
        float p2 = read_lane_f(p, 47);
        float p3 = read_lane_f(p, 63);
        l += (p0 + p1) + (p2 + p3);
        #pragma unroll
        for (int j = 0; j < 8; ++j)
            c[j] += p0 * e[0][j] + p1 * e[1][j] + p2 * e[2][j] + p3 * e[3][j];
    };

    // peeled first iteration: wait for ALL (only tile 0 outstanding)
    asm volatile("s_waitcnt vmcnt(0)" ::: "memory");
    __builtin_amdgcn_sched_barrier(0);
    do_batch(0);
    for (int i = 1; i < NB; ++i) {
        // outstanding (issue order): [8 DMAs tile i, 1 store iter i-1].
        // vmcnt(1): all but the youngest (the store) complete => DMAs landed.
        asm volatile("s_waitcnt vmcnt(1)" ::: "memory");
        __builtin_amdgcn_sched_barrier(0);
        do_batch(i);
    }

    // ---- combine the block's 4 waves in LDS; write pc partial
    #pragma unroll
    for (int k = 0; k < 2; ++k) {
        #pragma unroll
        for (int j = 0; j < 4; ++j)
            sc[wave][k * 256 + 4 * lane + j] = c[k * 4 + j];
    }
    __syncthreads();

    const int pidx = b * S_CHUNKS + chunk;
    for (int d = tid; d < DD; d += 256) {
        pc[(size_t)pidx * DD + d] = (sc[0][d] + sc[1][d]) + (sc[2][d] + sc[3][d]);
    }

    // ---- last-block-done fused epilogue
    __threadfence();                      // release: pexp + pc visible device-wide
    if (tid == 0) s_last = (atomicAdd(&cnt[b], 1) == S_CHUNKS - 1);
    __syncthreads();
    if (!s_last) return;
    __threadfence();                      // acquire: see all 16 blocks' writes

    // l = sum over pexp[b, :]
    float s2 = 0.f;
    #pragma unroll
    for (int k = 0; k < TT / 256; ++k) s2 += pexp[(size_t)b * TT + k * 256 + tid];
    #pragma unroll
    for (int off = 1; off < 64; off <<= 1) s2 += __shfl_xor(s2, off, 64);
    if (lane == 0) sl[wave] = s2;
    __syncthreads();
    const float linv = 1.0f / ((sl[0] + sl[1]) + (sl[2] + sl[3]));

    for (int d = tid; d < DD; d += 256) {
        float v = 0.f;
        #pragma unroll
        for (int ss = 0; ss < S_CHUNKS; ++ss)
            v += pc[((size_t)(b * S_CHUNKS + ss)) * DD + d];
        ctx_out[(size_t)b * DD + d] = v * linv;
    }
    for (int t = tid; t < TT; t += 256)
        wout[(size_t)b * TT + t] = pexp[(size_t)b * TT + t] * linv;
}

extern "C" void kernel_launch(void* const* d_in, const int* in_sizes, int n_in,
                              void* d_out, int out_size, void* d_ws, size_t ws_size,
                              hipStream_t stream) {
    const float* Eo   = (const float*)d_in[0];
    const float* H    = (const float*)d_in[1];
    const float* W_eo = (const float*)d_in[2];
    const float* b_eo = (const float*)d_in[3];
    const float* W_h  = (const float*)d_in[4];
    const float* b_h  = (const float*)d_in[5];
    const float* W_s  = (const float*)d_in[6];
    const float* b_s  = (const float*)d_in[7];

    // ws layout (floats): pexp[B*T] | pc[B*S*D] | cnt[B] (as ints)
    float* pexp = (float*)d_ws;
    float* pc   = pexp + (size_t)BB * TT;
    int*   cnt  = (int*)(pc + (size_t)BB * S_CHUNKS * DD);

    float* out_ctx = (float*)d_out;                 // [B, D]
    float* out_w   = out_ctx + (size_t)BB * DD;     // [B, T, 1]

    zero_cnt<<<1, 64, 0, stream>>>(cnt);
    dim3 gridA(S_CHUNKS, BB);
    attn_fused<<<gridA, 256, 0, stream>>>(Eo, H, W_eo, b_eo, W_h, b_h, W_s, b_s,
                                          pexp, pc, cnt, out_ctx, out_w);
}

// Round 14
// 61.936 us; speedup vs baseline: 3.6717x; 3.6717x over previous
//
#include <hip/hip_runtime.h>
#include <math.h>

#define BB 64
#define TT 2048
#define DD 512
#define UU 10
#define S_CHUNKS 8
#define CHUNK_T (TT / S_CHUNKS)   // 256 t per block, 64 per wave, 16 batches of 4
#define NB (CHUNK_T / 16)         // 16 batches per wave

__device__ __forceinline__ float fast_tanh(float x) {
    // tanh(x) = 1 - 2/(1+e^{2x}); robust at +-inf
    return 1.0f - 2.0f / (1.0f + __expf(2.0f * x));
}

// DPP row_shr:K accumulate (VALU pipe). Proven R5/R9/R10/R12.
template<int K>
__device__ __forceinline__ float dpp_shr(float x) {
    int xi = __builtin_bit_cast(int, x);
    int r  = __builtin_amdgcn_update_dpp(0, xi, 0x110 | K, 0xF, 0xF, true);
    return __builtin_bit_cast(float, r);
}

__device__ __forceinline__ float read_lane_f(float v, int lane) {
    return __builtin_bit_cast(float,
        __builtin_amdgcn_readlane(__builtin_bit_cast(int, v), lane));
}

// Async global->LDS DMA, 16B per lane (proven R12 with vmcnt(1) discipline).
typedef __attribute__((address_space(1))) const void gvoid;
typedef __attribute__((address_space(3))) void lvoid;
__device__ __forceinline__ void dma16(const float* g, float* l) {
    __builtin_amdgcn_global_load_lds((gvoid*)g, (lvoid*)l, 16, 0, 0);
}

// R14 = R12 exactly, with S_CHUNKS 16->8: 512 blocks = ONE residency round
// (2 blocks/CU x 256 CUs), half the block preambles, pc halved. Inner loop
// byte-identical; two-kernel split kept (R13: fusing the epilogue into this
// kernel made the allocator rematerialize wv -> 96 VGPR, 5x slowdown).
// Bandwidth evidence (R5 == R12 within noise; FETCH 133MB; ~4.8 TB/s
// combined read): pass1 is memory-bound, so only seams remain.
__global__ __launch_bounds__(256) void attn_pass1(
    const float* __restrict__ Eo, const float* __restrict__ H,
    const float* __restrict__ W_eo, const float* __restrict__ b_eo,
    const float* __restrict__ W_h, const float* __restrict__ b_h,
    const float* __restrict__ W_s, const float* __restrict__ b_s,
    float* __restrict__ pexp, float* __restrict__ pc)
{
    const int b     = blockIdx.y;
    const int chunk = blockIdx.x;
    const int tid   = threadIdx.x;
    const int wave  = tid >> 6;
    const int lane  = tid & 63;

    __shared__ __align__(16) float buf[4][2][4][DD];  // 64 KB: per-wave dbuf tiles
    __shared__ float sc[4][DD];                        // 8 KB: wave combine

    // ---- hb[u] = (H[b]*W_h)[u] + b_h[u] + b_eo[u]  (once per wave)
    float hacc[UU];
    #pragma unroll
    for (int u = 0; u < UU; ++u) hacc[u] = 0.f;
    const float* Hb = H + (size_t)b * DD;
    #pragma unroll
    for (int k = 0; k < DD / 64; ++k) {
        float hv = Hb[k * 64 + lane];
        const float* wr = W_h + (size_t)(k * 64 + lane) * UU;
        #pragma unroll
        for (int u = 0; u < UU; ++u) hacc[u] += hv * wr[u];
    }
    #pragma unroll
    for (int off = 1; off < 64; off <<= 1) {
        #pragma unroll
        for (int u = 0; u < UU; ++u) hacc[u] += __shfl_xor(hacc[u], off, 64);
    }
    float hb[UU];
    #pragma unroll
    for (int u = 0; u < UU; ++u) hb[u] = hacc[u] + b_h[u] + b_eo[u];

    float wsv[UU];
    #pragma unroll
    for (int u = 0; u < UU; ++u) wsv[u] = W_s[u];   // uniform -> scalar loads
    const float bs = b_s[0];

    // ---- per-lane W_eo slice (80 VGPRs, loaded once, reused for all t)
    float wv[8][UU];
    #pragma unroll
    for (int k = 0; k < 2; ++k) {
        #pragma unroll
        for (int j = 0; j < 4; ++j) {
            const float* wr = W_eo + (size_t)(k * 256 + 4 * lane + j) * UU;
            #pragma unroll
            for (int u = 0; u < UU; ++u) wv[k * 4 + j][u] = wr[u];
        }
    }

    float l = 0.f;
    float c[8];
    #pragma unroll
    for (int j = 0; j < 8; ++j) c[j] = 0.f;

    const int  t0w  = chunk * CHUNK_T + wave * (CHUNK_T / 4);
    const bool lo32 = (lane & 32) == 0;
    const bool lo16 = (lane & 16) == 0;
    const float* rowb = Eo + (size_t)b * TT * DD + 4 * lane;   // per-lane src

    // ---- prologue: DMA tile 0
    #pragma unroll
    for (int tt = 0; tt < 4; ++tt) {
        const float* g = rowb + (size_t)(t0w + tt) * DD;
        dma16(g,       &buf[wave][0][tt][0]);
        dma16(g + 256, &buf[wave][0][tt][256]);
    }

    auto do_batch = [&](int i) {
        const int cur = i & 1, nxt = cur ^ 1;
        // issue next tile's DMAs first (hidden under this batch's compute)
        if (i + 1 < NB) {
            #pragma unroll
            for (int tt = 0; tt < 4; ++tt) {
                const float* g = rowb + (size_t)(t0w + (i + 1) * 4 + tt) * DD;
                dma16(g,       &buf[wave][nxt][tt][0]);
                dma16(g + 256, &buf[wave][nxt][tt][256]);
            }
        }
        __builtin_amdgcn_sched_barrier(0);   // pin issues before compute

        const int tb = t0w + i * 4;
        float e[4][8];
        #pragma unroll
        for (int tt = 0; tt < 4; ++tt) {
            float4 e0 = *(const float4*)&buf[wave][cur][tt][4 * lane];
            float4 e1 = *(const float4*)&buf[wave][cur][tt][256 + 4 * lane];
            e[tt][0] = e0.x; e[tt][1] = e0.y; e[tt][2] = e0.z; e[tt][3] = e0.w;
            e[tt][4] = e1.x; e[tt][5] = e1.y; e[tt][6] = e1.z; e[tt][7] = e1.w;
        }

        float acc[4][UU];
        #pragma unroll
        for (int tt = 0; tt < 4; ++tt) {
            #pragma unroll
            for (int u = 0; u < UU; ++u) acc[tt][u] = 0.f;
            #pragma unroll
            for (int j = 0; j < 8; ++j) {
                #pragma unroll
                for (int u = 0; u < UU; ++u) acc[tt][u] += e[tt][j] * wv[j][u];
            }
        }

        // fold-reduce (R5-proven): select+xor32 x2, select+xor16, 4x DPP
        float s = bs;
        #pragma unroll
        for (int u = 0; u < UU; ++u) {
            float y0 = lo32 ? acc[0][u] : acc[2][u];
            float o0 = lo32 ? acc[2][u] : acc[0][u];
            y0 += __shfl_xor(o0, 32, 64);
            float y1 = lo32 ? acc[1][u] : acc[3][u];
            float o1 = lo32 ? acc[3][u] : acc[1][u];
            y1 += __shfl_xor(o1, 32, 64);
            float z  = lo16 ? y0 : y1;
            float oz = lo16 ? y1 : y0;
            z += __shfl_xor(oz, 16, 64);
            z += dpp_shr<1>(z);
            z += dpp_shr<2>(z);
            z += dpp_shr<4>(z);
            z += dpp_shr<8>(z);
            s += wsv[u] * fast_tanh(z + hb[u]);
        }
        float p = __expf(s);

        if ((lane & 15) == 15) pexp[(size_t)b * TT + tb + (lane >> 4)] = p;

        float p0 = read_lane_f(p, 15);
        float p1 = read_lane_f(p, 31);
        float p2 = read_lane_f(p, 47);
        float p3 = read_lane_f(p, 63);
        l += (p0 + p1) + (p2 + p3);
        #pragma unroll
        for (int j = 0; j < 8; ++j)
            c[j] += p0 * e[0][j] + p1 * e[1][j] + p2 * e[2][j] + p3 * e[3][j];
    };

    // peeled first iteration: wait for ALL (only tile 0 outstanding)
    asm volatile("s_waitcnt vmcnt(0)" ::: "memory");
    __builtin_amdgcn_sched_barrier(0);
    do_batch(0);
    for (int i = 1; i < NB; ++i) {
        // outstanding (issue order): [8 DMAs tile i, 1 store iter i-1].
        // vmcnt(1): all but the youngest (the store) complete => DMAs landed.
        asm volatile("s_waitcnt vmcnt(1)" ::: "memory");
        __builtin_amdgcn_sched_barrier(0);
        do_batch(i);
    }

    // ---- combine the block's 4 waves in LDS
    #pragma unroll
    for (int k = 0; k < 2; ++k) {
        #pragma unroll
        for (int j = 0; j < 4; ++j)
            sc[wave][k * 256 + 4 * lane + j] = c[k * 4 + j];
    }
    __syncthreads();

    const int pidx = b * S_CHUNKS + chunk;
    for (int d = tid; d < DD; d += 256) {
        pc[(size_t)pidx * DD + d] = (sc[0][d] + sc[1][d]) + (sc[2][d] + sc[3][d]);
    }
}

// Fused epilogue, 4 blocks per batch b (R9/R10/R12-proven)
__global__ __launch_bounds__(256) void attn_epilogue(
    const float* __restrict__ pexp, const float* __restrict__ pc,
    float* __restrict__ ctx_out, float* __restrict__ wout)
{
    const int b    = blockIdx.x >> 2;
    const int part = blockIdx.x & 3;
    const int tid  = threadIdx.x;
    const int wave = tid >> 6;

    float s = 0.f;
    #pragma unroll
    for (int k = 0; k < TT / 256; ++k) s += pexp[(size_t)b * TT + k * 256 + tid];
    #pragma unroll
    for (int off = 1; off < 64; off <<= 1) s += __shfl_xor(s, off, 64);

    __shared__ float sl[4];
    if ((tid & 63) == 0) sl[wave] = s;
    __syncthreads();
    const float l = (sl[0] + sl[1]) + (sl[2] + sl[3]);
    const float inv = 1.0f / l;

    const int d = part * (DD / 4) + tid;
    if (tid < DD / 4) {
        float v = 0.f;
        #pragma unroll
        for (int sss = 0; sss < S_CHUNKS; ++sss)
            v += pc[((size_t)(b * S_CHUNKS + sss)) * DD + d];
        ctx_out[(size_t)b * DD + d] = v * inv;
    }
    #pragma unroll
    for (int k = 0; k < 2; ++k) {
        const int t = part * (TT / 4) + k * 256 + tid;
        wout[(size_t)b * TT + t] = pexp[(size_t)b * TT + t] * inv;
    }
}

extern "C" void kernel_launch(void* const* d_in, const int* in_sizes, int n_in,
                              void* d_out, int out_size, void* d_ws, size_t ws_size,
                              hipStream_t stream) {
    const float* Eo   = (const float*)d_in[0];
    const float* H    = (const float*)d_in[1];
    const float* W_eo = (const float*)d_in[2];
    const float* b_eo = (const float*)d_in[3];
    const float* W_h  = (const float*)d_in[4];
    const float* b_h  = (const float*)d_in[5];
    const float* W_s  = (const float*)d_in[6];
    const float* b_s  = (const float*)d_in[7];

    // ws layout (floats): pexp[B*T] | pc[B*S*D]
    float* pexp = (float*)d_ws;
    float* pc   = pexp + (size_t)BB * TT;

    float* out_ctx = (float*)d_out;                 // [B, D]
    float* out_w   = out_ctx + (size_t)BB * DD;     // [B, T, 1]

    dim3 gridA(S_CHUNKS, BB);
    attn_pass1<<<gridA, 256, 0, stream>>>(Eo, H, W_eo, b_eo, W_h, b_h, W_s, b_s,
                                          pexp, pc);
    attn_epilogue<<<BB * 4, 256, 0, stream>>>(pexp, pc, out_ctx, out_w);
}